// Round 5
// baseline (360.555 us; speedup 1.0000x reference)
//
#include <hip/hip_runtime.h>

// Problem constants
#define B_   4
#define SQS  2048
#define SKS  2048
#define DM   1024
#define H_   16
#define MT   8192      // B_*SQS tokens

typedef __attribute__((ext_vector_type(8))) short bf16x8;
typedef __attribute__((ext_vector_type(4))) float f32x4;

__device__ __forceinline__ float bf2f(unsigned int u) { return __uint_as_float(u << 16); }
__device__ __forceinline__ unsigned short f2bf(float f) {
  unsigned int u = __float_as_uint(f);
  return (unsigned short)((u + 0x7fffu + ((u >> 16) & 1u)) >> 16);
}
// pack two floats -> two bf16 (round-half-up): [hi16(b) : hi16(a)]
__device__ __forceinline__ unsigned int pk_bf16(float a, float b) {
  return __builtin_amdgcn_perm(__float_as_uint(b) + 0x8000u,
                               __float_as_uint(a) + 0x8000u, 0x07060302u);
}
// truncating pack (rounding bias pre-compensated in mask bias)
__device__ __forceinline__ unsigned int pk_trunc(float a, float b) {
  return __builtin_amdgcn_perm(__float_as_uint(b), __float_as_uint(a), 0x07060302u);
}
__device__ __forceinline__ float fexp2(float x) {
#if __has_builtin(__builtin_amdgcn_exp2f)
  return __builtin_amdgcn_exp2f(x);
#else
  return __expf(x * 0.69314718056f);
#endif
}
__device__ __forceinline__ void async16(const void* g, void* l) {
  __builtin_amdgcn_global_load_lds((const __attribute__((address_space(1))) unsigned int*)g,
                                   (__attribute__((address_space(3))) unsigned int*)l,
                                   16, 0, 0);
}
// unpack 8 bf16 (uint4) -> 8 floats
__device__ __forceinline__ void cvt8(uint4 u, float* f) {
  f[0] = bf2f(u.x & 0xffffu); f[1] = bf2f(u.x >> 16);
  f[2] = bf2f(u.y & 0xffffu); f[3] = bf2f(u.y >> 16);
  f[4] = bf2f(u.z & 0xffffu); f[5] = bf2f(u.z >> 16);
  f[6] = bf2f(u.w & 0xffffu); f[7] = bf2f(u.w >> 16);
}

// 1/sqrt(D) * log2(e): folded into K projection epilogue
#define KSCALE 0.0450842200f
// log2(1 + 2^-9): compensates truncating bf16 pack of P (cancels in l-normalization)
#define BIAS_UNMASKED 0.0028151213f

// ---------------------------------------------------------------------------
// Merged prep: grid-strided (2592 blocks).
// [0,2048): q/k/v fp32->bf16, 12 units each ; [2048,2560): W transpose x8 ;
// [2560,2592): mask bias.
// ---------------------------------------------------------------------------
__global__ __launch_bounds__(256)
void prep_all(const float* __restrict__ q, const float* __restrict__ k,
              const float* __restrict__ v, const int* __restrict__ mask,
              const float* __restrict__ Wq, const float* __restrict__ Wk,
              const float* __restrict__ Wv, const float* __restrict__ Wo,
              unsigned short* __restrict__ qi, unsigned short* __restrict__ ki,
              unsigned short* __restrict__ vi,
              unsigned short* __restrict__ Wqt, unsigned short* __restrict__ Wkt,
              unsigned short* __restrict__ Wvt, unsigned short* __restrict__ Wot,
              float* __restrict__ mskb)
{
  __shared__ float s[32][33];
  const int bx = blockIdx.x, tid = threadIdx.x;
  if (bx < 2048) {
#pragma unroll 1
    for (int it = 0; it < 12; it++) {
      const int i6 = it * 2048 + bx;           // unit in [0,24576)
      const int which = i6 >> 13, i = i6 & 8191;
      const float* src = (which == 0) ? q : (which == 1) ? k : v;
      unsigned short* dst = (which == 0) ? qi : (which == 1) ? ki : vi;
      size_t o = ((size_t)i * 256 + tid) * 4;
      float4 f = *(const float4*)(src + o);
      uint2 u;
      u.x = pk_bf16(f.x, f.y);
      u.y = pk_bf16(f.z, f.w);
      *(uint2*)(dst + o) = u;
    }
  } else if (bx < 2560) {
#pragma unroll 1
    for (int t8 = 0; t8 < 8; t8++) {
      const int idx = t8 * 512 + (bx - 2048);  // [0,4096)
      const int w = idx >> 10, t = idx & 1023;
      const int n0 = (t & 31) * 32, k0 = (t >> 5) * 32;
      const float* W = (w == 0) ? Wq : (w == 1) ? Wk : (w == 2) ? Wv : Wo;
      unsigned short* Wt = (w == 0) ? Wqt : (w == 1) ? Wkt : (w == 2) ? Wvt : Wot;
#pragma unroll
      for (int p = 0; p < 4; p++) {
        int c = p * 256 + tid;
        int r = c >> 5, cc = c & 31;
        s[r][cc] = W[(size_t)(k0 + r) * DM + n0 + cc];
      }
      __syncthreads();
#pragma unroll
      for (int p = 0; p < 4; p++) {
        int c = p * 256 + tid;
        int r = c >> 5, cc = c & 31;
        Wt[(size_t)(n0 + r) * DM + k0 + cc] = f2bf(s[cc][r]);
      }
      __syncthreads();   // protect LDS reuse next iteration
    }
  } else {
    int i = (bx - 2560) * 256 + tid;
    mskb[i] = mask[i] ? BIAS_UNMASKED : -1e30f;
  }
}

// ---------------------------------------------------------------------------
// Fused QKV GEMM, BK=64, XOR-swizzled staging, XCD-aware remap.
// z==1 (K) pre-scaled by KSCALE. z==2 (V) written in vT layout
// (transposed + per-64 key permutation pi(k) = (i&1)*32 + qd*8 + (i>>1)*4 + r)
// via LDS transpose -> coalesced 16B stores.
// ---------------------------------------------------------------------------
__global__ __launch_bounds__(256)
void qkv_gemm(const unsigned short* __restrict__ A0, const unsigned short* __restrict__ A1,
              const unsigned short* __restrict__ A2,
              const unsigned short* __restrict__ W0, const unsigned short* __restrict__ W1,
              const unsigned short* __restrict__ W2,
              const float* __restrict__ s0, const float* __restrict__ s1,
              const float* __restrict__ s2,
              unsigned short* __restrict__ o0, unsigned short* __restrict__ o1,
              unsigned short* __restrict__ vT)
{
  // grid = 1536 linear blocks; L%8 = XCD; per XCD: 24 (m,z)-tiles x 8 n-blocks
  const int L = blockIdx.x + (blockIdx.y << 3) + (blockIdx.z << 9);
  const int g = L & 7, i5 = L >> 3;
  const int nblk = i5 & 7;
  const int yz = (i5 >> 3) + g * 24;     // [0,192)
  const int mblk = yz & 63;
  const int z = yz >> 6;

  const unsigned short* A  = (z == 0) ? A0 : (z == 1) ? A1 : A2;
  const unsigned short* Wt = (z == 0) ? W0 : (z == 1) ? W1 : W2;
  const float* bias        = (z == 0) ? s0 : (z == 1) ? s1 : s2;

  __shared__ short SMEM[2 * 128 * 64];   // As | Bs ; reused as 4x8KB in z==2 epilogue
  short* As = SMEM;
  short* Bs = SMEM + 128 * 64;
  const int tid = threadIdx.x;
  const int m0 = mblk * 128, n0 = nblk * 128;
  const int wave = tid >> 6, ln = tid & 15, qd = (tid & 63) >> 4;
  const int wm = (wave >> 1) * 64, wn = (wave & 1) * 64;

  int srow[4], sgj[4];
#pragma unroll
  for (int u = 0; u < 4; u++) {
    int c = u * 256 + tid;
    srow[u] = c >> 3;
    sgj[u] = ((c & 7) ^ (srow[u] & 7)) * 8;
  }

  f32x4 acc[4][4];
  const f32x4 vzero = {0.f, 0.f, 0.f, 0.f};
#pragma unroll
  for (int i = 0; i < 4; i++)
#pragma unroll
    for (int j = 0; j < 4; j++) acc[i][j] = vzero;

  for (int k0 = 0; k0 < DM; k0 += 64) {
    __syncthreads();
#pragma unroll
    for (int u = 0; u < 4; u++) {
      int c = u * 256 + tid;
      async16(A  + (size_t)(m0 + srow[u]) * DM + k0 + sgj[u], (char*)As + c * 16);
      async16(Wt + (size_t)(n0 + srow[u]) * DM + k0 + sgj[u], (char*)Bs + c * 16);
    }
    __syncthreads();

#pragma unroll
    for (int kk = 0; kk < 2; kk++) {
      const int ch = ((kk * 4 + qd) ^ (ln & 7)) * 8;
      bf16x8 af[4], bfr[4];
#pragma unroll
      for (int i = 0; i < 4; i++)
        af[i] = *(const bf16x8*)(As + (wm + i * 16 + ln) * 64 + ch);
#pragma unroll
      for (int j = 0; j < 4; j++)
        bfr[j] = *(const bf16x8*)(Bs + (wn + j * 16 + ln) * 64 + ch);
#pragma unroll
      for (int i = 0; i < 4; i++)
#pragma unroll
        for (int j = 0; j < 4; j++)
          acc[i][j] = __builtin_amdgcn_mfma_f32_16x16x32_bf16(af[i], bfr[j], acc[i][j], 0, 0, 0);
    }
  }

  if (z != 2) {
    unsigned short* C = (z == 0) ? o0 : o1;
    const float sc = (z == 1) ? KSCALE : 1.0f;
#pragma unroll
    for (int j = 0; j < 4; j++) {
      int col = n0 + wn + j * 16 + ln;
      float bj = bias[col];
#pragma unroll
      for (int i = 0; i < 4; i++) {
        int row = m0 + wm + i * 16 + qd * 4;
#pragma unroll
        for (int r = 0; r < 4; r++)
          C[(size_t)(row + r) * DM + col] = f2bf((acc[i][j][r] + bj) * sc);
      }
    }
  } else {
    // ---- vT write via LDS transpose (coalesced) ----
    __syncthreads();                       // all waves done reading As/Bs
    short* W = SMEM + (wave << 12);        // 4096 shorts (8KB) per wave
#pragma unroll
    for (int j = 0; j < 4; j++) {
      int col = n0 + wn + j * 16 + ln;
      float bj = bias[col];
      int d = j * 16 + ln;
#pragma unroll
      for (int i = 0; i < 4; i++) {
        int c = (i & 1) * 8 + qd * 2 + ((i >> 1) & 1);
        int pc = c ^ (ln & 7);             // XOR-swizzle vs d&7 (d&7 == ln&7)
        uint2 u;
        u.x = pk_bf16(acc[i][j][0] + bj, acc[i][j][1] + bj);
        u.y = pk_bf16(acc[i][j][2] + bj, acc[i][j][3] + bj);
        *(uint2*)(W + d * 64 + pc * 4) = u;
      }
    }
    const int h  = 2 * nblk + (wave & 1);
    const int bb = (m0 + wm) >> 11;
    const int kg = (m0 + wm) & 2047;       // 64-aligned key-group base
    const int l  = tid & 63;
    unsigned short* vrow_base = vT + ((size_t)(bb * H_ + h) * 64) * SKS + kg;
#pragma unroll
    for (int it = 0; it < 8; it++) {
      int d = it * 8 + (l >> 3);
      int c2 = (l & 7) * 2;
      int pc0 = c2 ^ (d & 7), pc1 = (c2 + 1) ^ (d & 7);
      uint2 a  = *(const uint2*)(W + d * 64 + pc0 * 4);
      uint2 b2 = *(const uint2*)(W + d * 64 + pc1 * 4);
      uint4 o4 = {a.x, a.y, b2.x, b2.y};
      *(uint4*)(vrow_base + (size_t)d * SKS + c2 * 4) = o4;
    }
  }
}

// ---------------------------------------------------------------------------
// Single GEMM (Wo, ReLU option), BK=64 swizzled, XCD-aware remap
// ---------------------------------------------------------------------------
__global__ __launch_bounds__(256)
void gemm_bf16(const unsigned short* __restrict__ A,
               const unsigned short* __restrict__ Wt,
               const float* __restrict__ bias,
               unsigned short* __restrict__ C,
               int relu)
{
  const int L = blockIdx.x + (blockIdx.y << 3);
  const int g = L & 7, i5 = L >> 3;
  const int nblk = i5 & 7;
  const int mblk = (i5 >> 3) + (g << 3);

  __shared__ short As[128 * 64];
  __shared__ short Bs[128 * 64];
  const int tid = threadIdx.x;
  const int m0 = mblk * 128, n0 = nblk * 128;
  const int wave = tid >> 6, ln = tid & 15, qd = (tid & 63) >> 4;
  const int wm = (wave >> 1) * 64, wn = (wave & 1) * 64;

  int srow[4], sgj[4];
#pragma unroll
  for (int u = 0; u < 4; u++) {
    int c = u * 256 + tid;
    srow[u] = c >> 3;
    sgj[u] = ((c & 7) ^ (srow[u] & 7)) * 8;
  }

  f32x4 acc[4][4];
  const f32x4 vzero = {0.f, 0.f, 0.f, 0.f};
#pragma unroll
  for (int i = 0; i < 4; i++)
#pragma unroll
    for (int j = 0; j < 4; j++) acc[i][j] = vzero;

  for (int k0 = 0; k0 < DM; k0 += 64) {
    __syncthreads();
#pragma unroll
    for (int u = 0; u < 4; u++) {
      int c = u * 256 + tid;
      async16(A  + (size_t)(m0 + srow[u]) * DM + k0 + sgj[u], (char*)As + c * 16);
      async16(Wt + (size_t)(n0 + srow[u]) * DM + k0 + sgj[u], (char*)Bs + c * 16);
    }
    __syncthreads();

#pragma unroll
    for (int kk = 0; kk < 2; kk++) {
      const int ch = ((kk * 4 + qd) ^ (ln & 7)) * 8;
      bf16x8 af[4], bfr[4];
#pragma unroll
      for (int i = 0; i < 4; i++)
        af[i] = *(const bf16x8*)(As + (wm + i * 16 + ln) * 64 + ch);
#pragma unroll
      for (int j = 0; j < 4; j++)
        bfr[j] = *(const bf16x8*)(Bs + (wn + j * 16 + ln) * 64 + ch);
#pragma unroll
      for (int i = 0; i < 4; i++)
#pragma unroll
        for (int j = 0; j < 4; j++)
          acc[i][j] = __builtin_amdgcn_mfma_f32_16x16x32_bf16(af[i], bfr[j], acc[i][j], 0, 0, 0);
    }
  }

#pragma unroll
  for (int j = 0; j < 4; j++) {
    int col = n0 + wn + j * 16 + ln;
    float bj = bias[col];
#pragma unroll
    for (int i = 0; i < 4; i++) {
      int row = m0 + wm + i * 16 + qd * 4;
#pragma unroll
      for (int r = 0; r < 4; r++) {
        float v = acc[i][j][r] + bj;
        if (relu) v = fmaxf(v, 0.f);
        C[(size_t)(row + r) * DM + col] = f2bf(v);
      }
    }
  }
}

// ---------------------------------------------------------------------------
// Flash attention fwd, K-split=2. R5: OCCUPANCY RESTRUCTURE.
// Diagnosis: 80 accum regs + 108 VGPR ~= 188/wave -> 2 waves/SIMD -> pipes
// can't cross-cover (R1 pipelining and R2 interleave both failed because the
// limiter is wave count, not instruction order).
// Change: each wave handles 2 q-groups (32 q rows) instead of 4 -> accum 40
// regs; kf/btv loaded inline per-gq (8+4 live vs 32+16); target <=128 total
// via __launch_bounds__(256,4) -> 4 waves/SIMD, 4 blocks/CU (LDS 147KB).
// Block covers 128 q rows; grid 2048 (16,16,8), same XCD decode, same
// R1-proven stage/barrier schedule. Extra cost: +8 kf ds_read_b128/tile.
// Writes UNNORMALIZED O-half (bf16) + l (fp32); merge fused into LN1.
// ---------------------------------------------------------------------------
__global__ __launch_bounds__(256, 4)
void attn_fwd(const unsigned short* __restrict__ qp,
              const unsigned short* __restrict__ kp,
              const unsigned short* __restrict__ vT,
              const float* __restrict__ maskb,
              unsigned short* __restrict__ O0,   // [MT][DM] unnormalized, half 0
              unsigned short* __restrict__ O1,   // half 1
              float* __restrict__ lws)           // [2][(b*H+h)*SQS + q]
{
  __shared__ __align__(16) short Ks[2][64 * 64];  // [key][d], swizzled 16B chunks
  __shared__ __align__(16) short Vs[2][64 * 64];  // [d][k'],  swizzled 16B chunks
  __shared__ __align__(16) float bias_all[1024];  // bias for this block's keys

  const int tid = threadIdx.x;
  // grid = 2048 linear; L%8 = XCD; per XCD: 8 bh x (16 qblk x 2 half)
  const int L = blockIdx.x + (blockIdx.y << 4) + (blockIdx.z << 8);
  const int g = L & 7, i5 = L >> 3;               // i5 in [0,256)
  const int half = i5 & 1;
  const int qblk = (i5 >> 1) & 15;
  const int bh = (i5 >> 5) + (g << 3);            // [0,64)
  const int h = bh & 15, b = bh >> 4;
  const int q0 = qblk * 128;
  const int koff0 = half * (SKS / 2);
  const int wave = tid >> 6, ln = tid & 15, qd = (tid & 63) >> 4;

  // staging geometry: 64x64 bf16 tile = 512 16B-chunks, 8 chunks/row,
  // physical chunk j stores logical chunk j^(row&7) (XOR swizzle both sides)
  int sRow[2], sOff[2];
#pragma unroll
  for (int u = 0; u < 2; u++) {
    int c = u * 256 + tid;
    sRow[u] = c >> 3;
    sOff[u] = ((c & 7) ^ (sRow[u] & 7)) * 8;
  }

  const unsigned short* kbase = kp + (size_t)(b * SKS) * DM + (h << 6);
  const unsigned short* vbase = vT + (size_t)((b * H_ + h) * 64) * SKS;

  // hoist all 1024 keys' bias for this block (one coalesced float4/thread)
  *(float4*)(bias_all + tid * 4) = *(const float4*)(maskb + b * SKS + koff0 + tid * 4);

  // Q fragments: 2 q-groups x 2 d-halves (B-operand layout), once per block
  bf16x8 qf[2][2];
#pragma unroll
  for (int gq = 0; gq < 2; gq++) {
    const unsigned short* qrow =
        qp + (size_t)(b * SQS + q0 + wave * 32 + gq * 16 + ln) * DM + (h << 6);
    qf[gq][0] = *(const bf16x8*)(qrow + qd * 8);
    qf[gq][1] = *(const bf16x8*)(qrow + 32 + qd * 8);
  }

  union { bf16x8 v; unsigned int u[4]; } onesf;
  onesf.u[0] = onesf.u[1] = onesf.u[2] = onesf.u[3] = 0x3F803F80u;

  const f32x4 vzero = {0.f, 0.f, 0.f, 0.f};
  f32x4 oA[2][4], lacc[2];
#pragma unroll
  for (int gq = 0; gq < 2; gq++) {
    lacc[gq] = vzero;
#pragma unroll
    for (int t = 0; t < 4; t++) oA[gq][t] = vzero;
  }

  // prologue: stage tile 0
#pragma unroll
  for (int u = 0; u < 2; u++) {
    int c = u * 256 + tid;
    async16(kbase + (size_t)(koff0 + sRow[u]) * DM + sOff[u], (char*)Ks[0] + c * 16);
    async16(vbase + (size_t)sRow[u] * SKS + koff0 + sOff[u], (char*)Vs[0] + c * 16);
  }
  __syncthreads();   // vmcnt(0) drain + bias_all visible

  const int NT = SKS / 2 / 64;   // 16 tiles of 64 keys
  for (int kt = 0; kt < NT; kt++) {
    const int cur = kt & 1;
    // issue next tile's stage FIRST -> flies during compute
    if (kt + 1 < NT) {
      const int k1 = koff0 + (kt + 1) * 64;
#pragma unroll
      for (int u = 0; u < 2; u++) {
        int c = u * 256 + tid;
        async16(kbase + (size_t)(k1 + sRow[u]) * DM + sOff[u], (char*)Ks[cur ^ 1] + c * 16);
        async16(vbase + (size_t)sRow[u] * SKS + k1 + sOff[u], (char*)Vs[cur ^ 1] + c * 16);
      }
    }
    const short* Ksb = Ks[cur];
    const short* Vsb = Vs[cur];

    bf16x8 pf[2][2];
#pragma unroll
    for (int gq = 0; gq < 2; gq++) {
      f32x4 sS[4];
      __builtin_amdgcn_s_setprio(1);
#pragma unroll
      for (int t = 0; t < 4; t++) {
        // kf/btv loaded inline (live set 12 regs, not 48)
        const short* krow = Ksb + (t * 16 + ln) * 64;
        bf16x8 kf0 = *(const bf16x8*)(krow + ((0 + qd) ^ (ln & 7)) * 8);
        bf16x8 kf1 = *(const bf16x8*)(krow + ((4 + qd) ^ (ln & 7)) * 8);
        f32x4 btv = *(const f32x4*)(bias_all + kt * 64 + t * 16 + qd * 4);
        f32x4 a = __builtin_amdgcn_mfma_f32_16x16x32_bf16(kf0, qf[gq][0], btv, 0, 0, 0);
        sS[t]   = __builtin_amdgcn_mfma_f32_16x16x32_bf16(kf1, qf[gq][1], a,   0, 0, 0);
      }
      __builtin_amdgcn_s_setprio(0);
      float p[4][4];
#pragma unroll
      for (int t = 0; t < 4; t++) {
        p[t][0] = fexp2(sS[t][0]);
        p[t][1] = fexp2(sS[t][1]);
        p[t][2] = fexp2(sS[t][2]);
        p[t][3] = fexp2(sS[t][3]);
      }
      union { bf16x8 v; unsigned int u[4]; } P0, P1;
      P0.u[0] = pk_trunc(p[0][0], p[0][1]);
      P0.u[1] = pk_trunc(p[0][2], p[0][3]);
      P0.u[2] = pk_trunc(p[2][0], p[2][1]);
      P0.u[3] = pk_trunc(p[2][2], p[2][3]);
      P1.u[0] = pk_trunc(p[1][0], p[1][1]);
      P1.u[1] = pk_trunc(p[1][2], p[1][3]);
      P1.u[2] = pk_trunc(p[3][0], p[3][1]);
      P1.u[3] = pk_trunc(p[3][2], p[3][3]);
      pf[gq][0] = P0.v;
      pf[gq][1] = P1.v;
      lacc[gq] = __builtin_amdgcn_mfma_f32_16x16x32_bf16(pf[gq][0], onesf.v, lacc[gq], 0, 0, 0);
      lacc[gq] = __builtin_amdgcn_mfma_f32_16x16x32_bf16(pf[gq][1], onesf.v, lacc[gq], 0, 0, 0);
    }

    // ---- O += P V, V fragments shared across the 2 q-groups ----
    __builtin_amdgcn_s_setprio(1);
#pragma unroll
    for (int t2 = 0; t2 < 4; t2++) {
      const short* vrow = Vsb + (t2 * 16 + ln) * 64;
      bf16x8 vf0 = *(const bf16x8*)(vrow + (((0 + qd) ^ (ln & 7))) * 8);
      bf16x8 vf1 = *(const bf16x8*)(vrow + (((4 + qd) ^ (ln & 7))) * 8);
#pragma unroll
      for (int gq = 0; gq < 2; gq++) {
        oA[gq][t2] = __builtin_amdgcn_mfma_f32_16x16x32_bf16(pf[gq][0], vf0, oA[gq][t2], 0, 0, 0);
        oA[gq][t2] = __builtin_amdgcn_mfma_f32_16x16x32_bf16(pf[gq][1], vf1, oA[gq][t2], 0, 0, 0);
      }
    }
    __builtin_amdgcn_s_setprio(0);

    __syncthreads();   // single barrier/tile: drains next-tile stage + read fence
  }

  // ---- epilogue: store UNNORMALIZED O-half + l ----
  unsigned short* obuf = half ? O1 : O0;
  float* lbuf = lws + (size_t)half * (B_ * H_ * SQS);
#pragma unroll
  for (int gq = 0; gq < 2; gq++) {
    int qloc = q0 + wave * 32 + gq * 16 + qd * 4;
    if (ln == 0) {
#pragma unroll
      for (int r = 0; r < 4; r++)
        lbuf[(size_t)(b * H_ + h) * SQS + qloc + r] = lacc[gq][r];
    }
#pragma unroll
    for (int t2 = 0; t2 < 4; t2++)
#pragma unroll
      for (int r = 0; r < 4; r++) {
        size_t idx = (size_t)(b * SQS + qloc + r) * DM + (h << 6) + t2 * 16 + ln;
        obuf[idx] = f2bf(oA[gq][t2][r]);
      }
  }
}

// ---------------------------------------------------------------------------
// LayerNorm(qp + (O0+O1)/(l0+l1)) * g + b -> bf16 (fused K-split merge + LN1)
// One wave per row; no LDS, no __syncthreads.
// ---------------------------------------------------------------------------
__global__ __launch_bounds__(256)
void ln_merge(const unsigned short* __restrict__ Xa, const unsigned short* __restrict__ O0,
              const unsigned short* __restrict__ O1, const float* __restrict__ lws,
              const float* __restrict__ gamma, const float* __restrict__ beta,
              unsigned short* __restrict__ outb)
{
  const int wv = threadIdx.x >> 6, l = threadIdx.x & 63;
  const int row = blockIdx.x * 4 + wv;
  const int b = row >> 11, q = row & 2047;
  const int hh = l >> 2;                 // head of this lane's 16-col slice
  const size_t lidx = (size_t)(b * H_ + hh) * SQS + q;
  float la = lws[lidx], lb2 = lws[lidx + (size_t)(B_ * H_ * SQS)];
  float lsum = la + lb2;
  float linv = (lsum > 0.f) ? 1.0f / lsum : 0.f;

  const size_t base = (size_t)row * DM + l * 16;
  float fa[16], f0[16], f1[16], v[16];
  cvt8(*(const uint4*)(Xa + base),     fa);
  cvt8(*(const uint4*)(Xa + base + 8), fa + 8);
  cvt8(*(const uint4*)(O0 + base),     f0);
  cvt8(*(const uint4*)(O0 + base + 8), f0 + 8);
  cvt8(*(const uint4*)(O1 + base),     f1);
  cvt8(*(const uint4*)(O1 + base + 8), f1 + 8);
  float s = 0.f, s2 = 0.f;
#pragma unroll
  for (int e = 0; e < 16; e++) {
    v[e] = fa[e] + (f0[e] + f1[e]) * linv;
    s  += v[e];
    s2 += v[e] * v[e];
  }
#pragma unroll
  for (int off = 1; off < 64; off <<= 1) {
    s  += __shfl_xor(s, off);
    s2 += __shfl_xor(s2, off);
  }
  float mean = s * (1.0f / 1024.0f);
  float var  = s2 * (1.0f / 1024.0f) - mean * mean;
  float rstd = rsqrtf(var + 1e-6f);
  const int c = l * 16;
  unsigned int o[8];
#pragma unroll
  for (int e = 0; e < 8; e++) {
    float oa = (v[2 * e]     - mean) * rstd * gamma[c + 2 * e]     + beta[c + 2 * e];
    float ob = (v[2 * e + 1] - mean) * rstd * gamma[c + 2 * e + 1] + beta[c + 2 * e + 1];
    o[e] = pk_bf16(oa, ob);
  }
  uint4 o0v = {o[0], o[1], o[2], o[3]};
  uint4 o1v = {o[4], o[5], o[6], o[7]};
  *(uint4*)(outb + base)     = o0v;
  *(uint4*)(outb + base + 8) = o1v;
}

// ---------------------------------------------------------------------------
// LayerNorm(Xa + Xb) * g + b -> fp32 (final LN). One wave per row.
// ---------------------------------------------------------------------------
__global__ __launch_bounds__(256)
void ln_fuse(const unsigned short* __restrict__ Xa, const unsigned short* __restrict__ Xb,
             const float* __restrict__ gamma, const float* __restrict__ beta,
             float* __restrict__ outf)
{
  const int wv = threadIdx.x >> 6, l = threadIdx.x & 63;
  const int row = blockIdx.x * 4 + wv;
  const size_t base = (size_t)row * DM + l * 16;
  float fa[16], fb[16], v[16];
  cvt8(*(const uint4*)(Xa + base),     fa);
  cvt8(*(const uint4*)(Xa + base + 8), fa + 8);
  cvt8(*(const uint4*)(Xb + base),     fb);
  cvt8(*(const uint4*)(Xb + base + 8), fb + 8);
  float s = 0.f, s2 = 0.f;
#pragma unroll
  for (int e = 0; e < 16; e++) {
    v[e] = fa[e] + fb[e];
    s  += v[e];
    s2 += v[e] * v[e];
  }
#pragma unroll
  for (int off = 1; off < 64; off <<= 1) {
    s  += __shfl_xor(s, off);
    s2 += __shfl_xor(s2, off);
  }
  float mean = s * (1.0f / 1024.0f);
  float var  = s2 * (1.0f / 1024.0f) - mean * mean;
  float rstd = rsqrtf(var + 1e-6f);
  const int c = l * 16;
#pragma unroll
  for (int e4 = 0; e4 < 4; e4++) {
    float4 ov;
    ov.x = (v[4 * e4 + 0] - mean) * rstd * gamma[c + 4 * e4 + 0] + beta[c + 4 * e4 + 0];
    ov.y = (v[4 * e4 + 1] - mean) * rstd * gamma[c + 4 * e4 + 1] + beta[c + 4 * e4 + 1];
    ov.z = (v[4 * e4 + 2] - mean) * rstd * gamma[c + 4 * e4 + 2] + beta[c + 4 * e4 + 2];
    ov.w = (v[4 * e4 + 3] - mean) * rstd * gamma[c + 4 * e4 + 3] + beta[c + 4 * e4 + 3];
    *(float4*)(outf + base + 4 * e4) = ov;
  }
}

// ---------------------------------------------------------------------------
extern "C" void kernel_launch(void* const* d_in, const int* in_sizes, int n_in,
                              void* d_out, int out_size, void* d_ws, size_t ws_size,
                              hipStream_t stream)
{
  (void)in_sizes; (void)n_in; (void)out_size; (void)ws_size;
  const float* q    = (const float*)d_in[0];
  const float* k    = (const float*)d_in[1];
  const float* v    = (const float*)d_in[2];
  const int*   mask = (const int*)  d_in[3];
  const float* Wq   = (const float*)d_in[4];
  const float* bq   = (const float*)d_in[5];
  const float* Wk   = (const float*)d_in[6];
  const float* bk   = (const float*)d_in[7];
  const float* Wv   = (const float*)d_in[8];
  const float* bv   = (const float*)d_in[9];
  const float* Wo   = (const float*)d_in[10];
  const float* bo   = (const float*)d_in[11];
  const float* g1   = (const float*)d_in[12];
  const float* b1   = (const float*)d_in[13];
  const float* g2   = (const float*)d_in[14];
  const float* b2   = (const float*)d_in[15];

  char* ws = (char*)d_ws;
  const size_t SZ16 = (size_t)16 << 20;
  unsigned short* qi   = (unsigned short*)(ws + 0 * SZ16);
  unsigned short* ki   = (unsigned short*)(ws + 1 * SZ16);
  unsigned short* vi   = (unsigned short*)(ws + 2 * SZ16);
  unsigned short* qpb  = (unsigned short*)(ws + 3 * SZ16);
  unsigned short* kpb  = (unsigned short*)(ws + 4 * SZ16);
  unsigned short* vTb  = (unsigned short*)(ws + 6 * SZ16);
  unsigned short* Wqt  = (unsigned short*)(ws + 7 * SZ16 + ((size_t)0 << 20));
  unsigned short* Wkt  = (unsigned short*)(ws + 7 * SZ16 + ((size_t)2 << 20));
  unsigned short* Wvt  = (unsigned short*)(ws + 7 * SZ16 + ((size_t)4 << 20));
  unsigned short* Wot  = (unsigned short*)(ws + 7 * SZ16 + ((size_t)6 << 20));
  float*          mskb = (float*)         (ws + 7 * SZ16 + ((size_t)8 << 20));
  float*          lws  = (float*)         (ws + 7 * SZ16 + ((size_t)9 << 20));  // 2x512KB
  // dead-buffer reuse:
  unsigned short* O0b  = qi;    // free after qkv
  unsigned short* O1b  = vi;    // free after qkv
  unsigned short* xb   = ki;    // free after qkv
  unsigned short* hb   = vTb;   // free after attn

  prep_all     <<<2592,             256, 0, stream>>>(q, k, v, mask, Wq, Wk, Wv, Wo,
                                                      qi, ki, vi, Wqt, Wkt, Wvt, Wot, mskb);

  qkv_gemm     <<<dim3(8, 64, 3),   256, 0, stream>>>(qi, ki, vi, Wqt, Wkt, Wvt,
                                                      bq, bk, bv, qpb, kpb, vTb);

  attn_fwd     <<<dim3(16, 16, 8),  256, 0, stream>>>(qpb, kpb, vTb, mskb, O0b, O1b, lws);

  ln_merge     <<<2048,             256, 0, stream>>>(qpb, O0b, O1b, lws, g1, b1, xb);
  gemm_bf16    <<<dim3(8, 64),      256, 0, stream>>>(xb, Wot, bo, hb, 1);
  ln_fuse      <<<2048,             256, 0, stream>>>(xb, hb, g2, b2, (float*)d_out);
}

// Round 6
// 347.322 us; speedup vs baseline: 1.0381x; 1.0381x over previous
//
#include <hip/hip_runtime.h>

// Problem constants
#define B_   4
#define SQS  2048
#define SKS  2048
#define DM   1024
#define H_   16
#define MT   8192      // B_*SQS tokens

typedef __attribute__((ext_vector_type(8))) short bf16x8;
typedef __attribute__((ext_vector_type(4))) float f32x4;

__device__ __forceinline__ float bf2f(unsigned int u) { return __uint_as_float(u << 16); }
__device__ __forceinline__ unsigned short f2bf(float f) {
  unsigned int u = __float_as_uint(f);
  return (unsigned short)((u + 0x7fffu + ((u >> 16) & 1u)) >> 16);
}
// pack two floats -> two bf16 (round-half-up): [hi16(b) : hi16(a)]
__device__ __forceinline__ unsigned int pk_bf16(float a, float b) {
  return __builtin_amdgcn_perm(__float_as_uint(b) + 0x8000u,
                               __float_as_uint(a) + 0x8000u, 0x07060302u);
}
// truncating pack (rounding bias pre-compensated in mask bias)
__device__ __forceinline__ unsigned int pk_trunc(float a, float b) {
  return __builtin_amdgcn_perm(__float_as_uint(b), __float_as_uint(a), 0x07060302u);
}
__device__ __forceinline__ float fexp2(float x) {
#if __has_builtin(__builtin_amdgcn_exp2f)
  return __builtin_amdgcn_exp2f(x);
#else
  return __expf(x * 0.69314718056f);
#endif
}
__device__ __forceinline__ void async16(const void* g, void* l) {
  __builtin_amdgcn_global_load_lds((const __attribute__((address_space(1))) unsigned int*)g,
                                   (__attribute__((address_space(3))) unsigned int*)l,
                                   16, 0, 0);
}
// unpack 8 bf16 (uint4) -> 8 floats
__device__ __forceinline__ void cvt8(uint4 u, float* f) {
  f[0] = bf2f(u.x & 0xffffu); f[1] = bf2f(u.x >> 16);
  f[2] = bf2f(u.y & 0xffffu); f[3] = bf2f(u.y >> 16);
  f[4] = bf2f(u.z & 0xffffu); f[5] = bf2f(u.z >> 16);
  f[6] = bf2f(u.w & 0xffffu); f[7] = bf2f(u.w >> 16);
}
// vT per-64-key column permutation (matches qkv z==2 epilogue layout)
__device__ __forceinline__ int colp(int g) {
  return ((g >> 4) & 1) * 32 + ((g >> 2) & 3) * 8 + ((g >> 5) & 1) * 4 + (g & 3);
}

// 1/sqrt(D) * log2(e): folded into K projection epilogue
#define KSCALE 0.0450842200f
// log2(1 + 2^-9): compensates truncating bf16 pack of P (cancels in l-normalization)
#define BIAS_UNMASKED 0.0028151213f

// ---------------------------------------------------------------------------
// Merged prep: grid-strided (2564 blocks).
// [0,2048): q/k/v fp32->bf16, 12 units each ; [2048,2560): W transpose x8 ;
// [2560,2564): per-batch mask compaction scan -> idx[b][j], cinfo[b]=count.
// (Masked keys contribute exp(-inf)=0 to softmax num/denom/PV -> attention
//  only needs the unmasked keys; order is irrelevant since the sums are
//  permutation-invariant.)
// ---------------------------------------------------------------------------
__global__ __launch_bounds__(256)
void prep_all(const float* __restrict__ q, const float* __restrict__ k,
              const float* __restrict__ v, const int* __restrict__ mask,
              const float* __restrict__ Wq, const float* __restrict__ Wk,
              const float* __restrict__ Wv, const float* __restrict__ Wo,
              unsigned short* __restrict__ qi, unsigned short* __restrict__ ki,
              unsigned short* __restrict__ vi,
              unsigned short* __restrict__ Wqt, unsigned short* __restrict__ Wkt,
              unsigned short* __restrict__ Wvt, unsigned short* __restrict__ Wot,
              int* __restrict__ idx, int* __restrict__ cinfo)
{
  __shared__ float s[32][33];
  __shared__ int lcnt;
  const int bx = blockIdx.x, tid = threadIdx.x;
  if (bx < 2048) {
#pragma unroll 1
    for (int it = 0; it < 12; it++) {
      const int i6 = it * 2048 + bx;           // unit in [0,24576)
      const int which = i6 >> 13, i = i6 & 8191;
      const float* src = (which == 0) ? q : (which == 1) ? k : v;
      unsigned short* dst = (which == 0) ? qi : (which == 1) ? ki : vi;
      size_t o = ((size_t)i * 256 + tid) * 4;
      float4 f = *(const float4*)(src + o);
      uint2 u;
      u.x = pk_bf16(f.x, f.y);
      u.y = pk_bf16(f.z, f.w);
      *(uint2*)(dst + o) = u;
    }
  } else if (bx < 2560) {
#pragma unroll 1
    for (int t8 = 0; t8 < 8; t8++) {
      const int idx2 = t8 * 512 + (bx - 2048);  // [0,4096)
      const int w = idx2 >> 10, t = idx2 & 1023;
      const int n0 = (t & 31) * 32, k0 = (t >> 5) * 32;
      const float* W = (w == 0) ? Wq : (w == 1) ? Wk : (w == 2) ? Wv : Wo;
      unsigned short* Wt = (w == 0) ? Wqt : (w == 1) ? Wkt : (w == 2) ? Wvt : Wot;
#pragma unroll
      for (int p = 0; p < 4; p++) {
        int c = p * 256 + tid;
        int r = c >> 5, cc = c & 31;
        s[r][cc] = W[(size_t)(k0 + r) * DM + n0 + cc];
      }
      __syncthreads();
#pragma unroll
      for (int p = 0; p < 4; p++) {
        int c = p * 256 + tid;
        int r = c >> 5, cc = c & 31;
        Wt[(size_t)(n0 + r) * DM + k0 + cc] = f2bf(s[cc][r]);
      }
      __syncthreads();   // protect LDS reuse next iteration
    }
  } else {
    // mask compaction scan for batch b (order-free via LDS atomic)
    const int b = bx - 2560;
    if (tid == 0) lcnt = 0;
    __syncthreads();
#pragma unroll
    for (int e = 0; e < 8; e++) {
      int kk = tid * 8 + e;
      if (mask[b * SKS + kk]) {
        int j = atomicAdd(&lcnt, 1);
        idx[b * SKS + j] = kk;
      }
    }
    __syncthreads();
    if (tid == 0) cinfo[b] = lcnt;
  }
}

// ---------------------------------------------------------------------------
// Fused QKV GEMM, BK=64, XOR-swizzled staging, XCD-aware remap.
// z==1 (K) pre-scaled by KSCALE. z==2 (V) written in vT layout
// (transposed + per-64 key permutation colp) via LDS transpose.
// ---------------------------------------------------------------------------
__global__ __launch_bounds__(256)
void qkv_gemm(const unsigned short* __restrict__ A0, const unsigned short* __restrict__ A1,
              const unsigned short* __restrict__ A2,
              const unsigned short* __restrict__ W0, const unsigned short* __restrict__ W1,
              const unsigned short* __restrict__ W2,
              const float* __restrict__ s0, const float* __restrict__ s1,
              const float* __restrict__ s2,
              unsigned short* __restrict__ o0, unsigned short* __restrict__ o1,
              unsigned short* __restrict__ vT)
{
  // grid = 1536 linear blocks; L%8 = XCD; per XCD: 24 (m,z)-tiles x 8 n-blocks
  const int L = blockIdx.x + (blockIdx.y << 3) + (blockIdx.z << 9);
  const int g = L & 7, i5 = L >> 3;
  const int nblk = i5 & 7;
  const int yz = (i5 >> 3) + g * 24;     // [0,192)
  const int mblk = yz & 63;
  const int z = yz >> 6;

  const unsigned short* A  = (z == 0) ? A0 : (z == 1) ? A1 : A2;
  const unsigned short* Wt = (z == 0) ? W0 : (z == 1) ? W1 : W2;
  const float* bias        = (z == 0) ? s0 : (z == 1) ? s1 : s2;

  __shared__ short SMEM[2 * 128 * 64];   // As | Bs ; reused as 4x8KB in z==2 epilogue
  short* As = SMEM;
  short* Bs = SMEM + 128 * 64;
  const int tid = threadIdx.x;
  const int m0 = mblk * 128, n0 = nblk * 128;
  const int wave = tid >> 6, ln = tid & 15, qd = (tid & 63) >> 4;
  const int wm = (wave >> 1) * 64, wn = (wave & 1) * 64;

  int srow[4], sgj[4];
#pragma unroll
  for (int u = 0; u < 4; u++) {
    int c = u * 256 + tid;
    srow[u] = c >> 3;
    sgj[u] = ((c & 7) ^ (srow[u] & 7)) * 8;
  }

  f32x4 acc[4][4];
  const f32x4 vzero = {0.f, 0.f, 0.f, 0.f};
#pragma unroll
  for (int i = 0; i < 4; i++)
#pragma unroll
    for (int j = 0; j < 4; j++) acc[i][j] = vzero;

  for (int k0 = 0; k0 < DM; k0 += 64) {
    __syncthreads();
#pragma unroll
    for (int u = 0; u < 4; u++) {
      int c = u * 256 + tid;
      async16(A  + (size_t)(m0 + srow[u]) * DM + k0 + sgj[u], (char*)As + c * 16);
      async16(Wt + (size_t)(n0 + srow[u]) * DM + k0 + sgj[u], (char*)Bs + c * 16);
    }
    __syncthreads();

#pragma unroll
    for (int kk = 0; kk < 2; kk++) {
      const int ch = ((kk * 4 + qd) ^ (ln & 7)) * 8;
      bf16x8 af[4], bfr[4];
#pragma unroll
      for (int i = 0; i < 4; i++)
        af[i] = *(const bf16x8*)(As + (wm + i * 16 + ln) * 64 + ch);
#pragma unroll
      for (int j = 0; j < 4; j++)
        bfr[j] = *(const bf16x8*)(Bs + (wn + j * 16 + ln) * 64 + ch);
#pragma unroll
      for (int i = 0; i < 4; i++)
#pragma unroll
        for (int j = 0; j < 4; j++)
          acc[i][j] = __builtin_amdgcn_mfma_f32_16x16x32_bf16(af[i], bfr[j], acc[i][j], 0, 0, 0);
    }
  }

  if (z != 2) {
    unsigned short* C = (z == 0) ? o0 : o1;
    const float sc = (z == 1) ? KSCALE : 1.0f;
#pragma unroll
    for (int j = 0; j < 4; j++) {
      int col = n0 + wn + j * 16 + ln;
      float bj = bias[col];
#pragma unroll
      for (int i = 0; i < 4; i++) {
        int row = m0 + wm + i * 16 + qd * 4;
#pragma unroll
        for (int r = 0; r < 4; r++)
          C[(size_t)(row + r) * DM + col] = f2bf((acc[i][j][r] + bj) * sc);
      }
    }
  } else {
    // ---- vT write via LDS transpose (coalesced) ----
    __syncthreads();                       // all waves done reading As/Bs
    short* W = SMEM + (wave << 12);        // 4096 shorts (8KB) per wave
#pragma unroll
    for (int j = 0; j < 4; j++) {
      int col = n0 + wn + j * 16 + ln;
      float bj = bias[col];
      int d = j * 16 + ln;
#pragma unroll
      for (int i = 0; i < 4; i++) {
        int c = (i & 1) * 8 + qd * 2 + ((i >> 1) & 1);
        int pc = c ^ (ln & 7);             // XOR-swizzle vs d&7 (d&7 == ln&7)
        uint2 u;
        u.x = pk_bf16(acc[i][j][0] + bj, acc[i][j][1] + bj);
        u.y = pk_bf16(acc[i][j][2] + bj, acc[i][j][3] + bj);
        *(uint2*)(W + d * 64 + pc * 4) = u;
      }
    }
    const int h  = 2 * nblk + (wave & 1);
    const int bb = (m0 + wm) >> 11;
    const int kg = (m0 + wm) & 2047;       // 64-aligned key-group base
    const int l  = tid & 63;
    unsigned short* vrow_base = vT + ((size_t)(bb * H_ + h) * 64) * SKS + kg;
#pragma unroll
    for (int it = 0; it < 8; it++) {
      int d = it * 8 + (l >> 3);
      int c2 = (l & 7) * 2;
      int pc0 = c2 ^ (d & 7), pc1 = (c2 + 1) ^ (d & 7);
      uint2 a  = *(const uint2*)(W + d * 64 + pc0 * 4);
      uint2 b2 = *(const uint2*)(W + d * 64 + pc1 * 4);
      uint4 o4 = {a.x, a.y, b2.x, b2.y};
      *(uint4*)(vrow_base + (size_t)d * SKS + c2 * 4) = o4;
    }
  }
}

// ---------------------------------------------------------------------------
// Compaction: gather unmasked keys.
// Wave-tasks: [0,8192): kp row copy (b,j): kpc[b][j] = kpb[b][idx[j]], pad->0.
// [8192,12288): vT row gather (b,h,d): vTc col (j&~63)+colp(j&63) <-
//               vTb col (k&~63)+colp(k&63), k=idx[j]; pad->0.
// ---------------------------------------------------------------------------
__global__ __launch_bounds__(256)
void compact_kv(const unsigned short* __restrict__ kpb,
                const unsigned short* __restrict__ vTb,
                const int* __restrict__ idx, const int* __restrict__ cinfo,
                unsigned short* __restrict__ kpc,
                unsigned short* __restrict__ vTc)
{
  const int wave = threadIdx.x >> 6, ln = threadIdx.x & 63;
  const int task = blockIdx.x * 4 + wave;
  if (task < 8192) {
    const int b = task >> 11, j = task & 2047;
    const int cnt = cinfo[b];
    const int pad = (cnt + 63) & ~63;
    if (j >= pad) return;
    unsigned short* dst = kpc + ((size_t)b * SKS + j) * DM;
    if (j < cnt) {
      const unsigned short* src = kpb + ((size_t)b * SKS + idx[b * SKS + j]) * DM;
      uint4 a = *(const uint4*)(src + ln * 16);
      uint4 c = *(const uint4*)(src + ln * 16 + 8);
      *(uint4*)(dst + ln * 16)     = a;
      *(uint4*)(dst + ln * 16 + 8) = c;
    } else {
      uint4 zz = {0u, 0u, 0u, 0u};
      *(uint4*)(dst + ln * 16)     = zz;
      *(uint4*)(dst + ln * 16 + 8) = zz;
    }
  } else {
    const int t2 = task - 8192;            // [0,4096) = (b*H+h)*64+d
    const int b = t2 >> 10;
    const int cnt = cinfo[b];
    const int pad = (cnt + 63) & ~63;
    const unsigned short* src = vTb + (size_t)t2 * SKS;
    unsigned short* dst = vTc + (size_t)t2 * SKS;
    const int cl = colp(ln);
    const int* idxb = idx + b * SKS;
#pragma unroll 1
    for (int j0 = 0; j0 < pad; j0 += 64) {
      int j = j0 + ln;
      unsigned short v = 0;
      if (j < cnt) {
        int kk = idxb[j];
        v = src[(kk & ~63) + colp(kk & 63)];
      }
      dst[j0 + cl] = v;
    }
  }
}

// ---------------------------------------------------------------------------
// Single GEMM (Wo, ReLU option), BK=64 swizzled, XCD-aware remap
// ---------------------------------------------------------------------------
__global__ __launch_bounds__(256)
void gemm_bf16(const unsigned short* __restrict__ A,
               const unsigned short* __restrict__ Wt,
               const float* __restrict__ bias,
               unsigned short* __restrict__ C,
               int relu)
{
  const int L = blockIdx.x + (blockIdx.y << 3);
  const int g = L & 7, i5 = L >> 3;
  const int nblk = i5 & 7;
  const int mblk = (i5 >> 3) + (g << 3);

  __shared__ short As[128 * 64];
  __shared__ short Bs[128 * 64];
  const int tid = threadIdx.x;
  const int m0 = mblk * 128, n0 = nblk * 128;
  const int wave = tid >> 6, ln = tid & 15, qd = (tid & 63) >> 4;
  const int wm = (wave >> 1) * 64, wn = (wave & 1) * 64;

  int srow[4], sgj[4];
#pragma unroll
  for (int u = 0; u < 4; u++) {
    int c = u * 256 + tid;
    srow[u] = c >> 3;
    sgj[u] = ((c & 7) ^ (srow[u] & 7)) * 8;
  }

  f32x4 acc[4][4];
  const f32x4 vzero = {0.f, 0.f, 0.f, 0.f};
#pragma unroll
  for (int i = 0; i < 4; i++)
#pragma unroll
    for (int j = 0; j < 4; j++) acc[i][j] = vzero;

  for (int k0 = 0; k0 < DM; k0 += 64) {
    __syncthreads();
#pragma unroll
    for (int u = 0; u < 4; u++) {
      int c = u * 256 + tid;
      async16(A  + (size_t)(m0 + srow[u]) * DM + k0 + sgj[u], (char*)As + c * 16);
      async16(Wt + (size_t)(n0 + srow[u]) * DM + k0 + sgj[u], (char*)Bs + c * 16);
    }
    __syncthreads();

#pragma unroll
    for (int kk = 0; kk < 2; kk++) {
      const int ch = ((kk * 4 + qd) ^ (ln & 7)) * 8;
      bf16x8 af[4], bfr[4];
#pragma unroll
      for (int i = 0; i < 4; i++)
        af[i] = *(const bf16x8*)(As + (wm + i * 16 + ln) * 64 + ch);
#pragma unroll
      for (int j = 0; j < 4; j++)
        bfr[j] = *(const bf16x8*)(Bs + (wn + j * 16 + ln) * 64 + ch);
#pragma unroll
      for (int i = 0; i < 4; i++)
#pragma unroll
        for (int j = 0; j < 4; j++)
          acc[i][j] = __builtin_amdgcn_mfma_f32_16x16x32_bf16(af[i], bfr[j], acc[i][j], 0, 0, 0);
    }
  }

#pragma unroll
  for (int j = 0; j < 4; j++) {
    int col = n0 + wn + j * 16 + ln;
    float bj = bias[col];
#pragma unroll
    for (int i = 0; i < 4; i++) {
      int row = m0 + wm + i * 16 + qd * 4;
#pragma unroll
      for (int r = 0; r < 4; r++) {
        float v = acc[i][j][r] + bj;
        if (relu) v = fmaxf(v, 0.f);
        C[(size_t)(row + r) * DM + col] = f2bf(v);
      }
    }
  }
}

// ---------------------------------------------------------------------------
// Flash attention fwd over COMPACTED keys (R6). No K-split: expected ~1024
// unmasked keys per batch -> NT = ceil(cnt/64) ~ 16 tiles (worst 32). Tile
// work halves vs R5. Bias computed in-register (slot<cnt ? B : -1e30); pad
// rows of kpc/vTc are zeroed (S=-1e30 -> p=0, exact). 2 q-groups/wave,
// VGPR~60, 4 waves/SIMD. Single unnormalized O + l; normalization in LN1.
// ---------------------------------------------------------------------------
__global__ __launch_bounds__(256, 4)
void attn_fwd(const unsigned short* __restrict__ qp,
              const unsigned short* __restrict__ kpc,
              const unsigned short* __restrict__ vTc,
              const int* __restrict__ cinfo,
              unsigned short* __restrict__ O0,   // [MT][DM] unnormalized
              float* __restrict__ lws)           // [(b*H+h)*SQS + q]
{
  __shared__ __align__(16) short Ks[2][64 * 64];  // [key][d], swizzled 16B chunks
  __shared__ __align__(16) short Vs[2][64 * 64];  // [d][k'],  swizzled 16B chunks

  const int tid = threadIdx.x;
  // grid = 1024 linear; L%8 = XCD; per XCD: 8 bh x 16 qblk
  const int L = blockIdx.x + (blockIdx.y << 4) + (blockIdx.z << 8);
  const int g = L & 7, i5 = L >> 3;               // i5 in [0,128)
  const int qblk = i5 & 15;
  const int bh = (i5 >> 4) + (g << 3);            // [0,64)
  const int h = bh & 15, b = bh >> 4;
  const int q0 = qblk * 128;
  const int wave = tid >> 6, ln = tid & 15, qd = (tid & 63) >> 4;

  const int cnt = cinfo[b];
  const int NT = (cnt + 63) >> 6;                 // dynamic tile count

  // staging geometry: 64x64 bf16 tile = 512 16B-chunks, 8 chunks/row,
  // physical chunk j stores logical chunk j^(row&7) (XOR swizzle both sides)
  int sRow[2], sOff[2];
#pragma unroll
  for (int u = 0; u < 2; u++) {
    int c = u * 256 + tid;
    sRow[u] = c >> 3;
    sOff[u] = ((c & 7) ^ (sRow[u] & 7)) * 8;
  }

  const unsigned short* kbase = kpc + (size_t)(b * SKS) * DM + (h << 6);
  const unsigned short* vbase = vTc + (size_t)((b * H_ + h) * 64) * SKS;

  // Q fragments: 2 q-groups x 2 d-halves (B-operand layout), once per block
  bf16x8 qf[2][2];
#pragma unroll
  for (int gq = 0; gq < 2; gq++) {
    const unsigned short* qrow =
        qp + (size_t)(b * SQS + q0 + wave * 32 + gq * 16 + ln) * DM + (h << 6);
    qf[gq][0] = *(const bf16x8*)(qrow + qd * 8);
    qf[gq][1] = *(const bf16x8*)(qrow + 32 + qd * 8);
  }

  union { bf16x8 v; unsigned int u[4]; } onesf;
  onesf.u[0] = onesf.u[1] = onesf.u[2] = onesf.u[3] = 0x3F803F80u;

  const f32x4 vzero = {0.f, 0.f, 0.f, 0.f};
  f32x4 oA[2][4], lacc[2];
#pragma unroll
  for (int gq = 0; gq < 2; gq++) {
    lacc[gq] = vzero;
#pragma unroll
    for (int t = 0; t < 4; t++) oA[gq][t] = vzero;
  }

  // prologue: stage tile 0 (if NT==0 the data is never consumed)
#pragma unroll
  for (int u = 0; u < 2; u++) {
    int c = u * 256 + tid;
    async16(kbase + (size_t)sRow[u] * DM + sOff[u], (char*)Ks[0] + c * 16);
    async16(vbase + (size_t)sRow[u] * SKS + sOff[u], (char*)Vs[0] + c * 16);
  }
  __syncthreads();   // vmcnt(0) drain

#pragma unroll 1
  for (int kt = 0; kt < NT; kt++) {
    const int cur = kt & 1;
    // issue next tile's stage FIRST -> flies during compute
    if (kt + 1 < NT) {
      const int k1 = (kt + 1) * 64;
#pragma unroll
      for (int u = 0; u < 2; u++) {
        int c = u * 256 + tid;
        async16(kbase + (size_t)(k1 + sRow[u]) * DM + sOff[u], (char*)Ks[cur ^ 1] + c * 16);
        async16(vbase + (size_t)sRow[u] * SKS + k1 + sOff[u], (char*)Vs[cur ^ 1] + c * 16);
      }
    }
    const short* Ksb = Ks[cur];
    const short* Vsb = Vs[cur];

    bf16x8 pf[2][2];
#pragma unroll
    for (int gq = 0; gq < 2; gq++) {
      f32x4 sS[4];
      __builtin_amdgcn_s_setprio(1);
#pragma unroll
      for (int t = 0; t < 4; t++) {
        // kf loaded inline; bias generated in-register from slot index
        const short* krow = Ksb + (t * 16 + ln) * 64;
        bf16x8 kf0 = *(const bf16x8*)(krow + ((0 + qd) ^ (ln & 7)) * 8);
        bf16x8 kf1 = *(const bf16x8*)(krow + ((4 + qd) ^ (ln & 7)) * 8);
        int jb = kt * 64 + t * 16 + qd * 4;
        f32x4 btv;
        btv[0] = (jb + 0 < cnt) ? BIAS_UNMASKED : -1e30f;
        btv[1] = (jb + 1 < cnt) ? BIAS_UNMASKED : -1e30f;
        btv[2] = (jb + 2 < cnt) ? BIAS_UNMASKED : -1e30f;
        btv[3] = (jb + 3 < cnt) ? BIAS_UNMASKED : -1e30f;
        f32x4 a = __builtin_amdgcn_mfma_f32_16x16x32_bf16(kf0, qf[gq][0], btv, 0, 0, 0);
        sS[t]   = __builtin_amdgcn_mfma_f32_16x16x32_bf16(kf1, qf[gq][1], a,   0, 0, 0);
      }
      __builtin_amdgcn_s_setprio(0);
      float p[4][4];
#pragma unroll
      for (int t = 0; t < 4; t++) {
        p[t][0] = fexp2(sS[t][0]);
        p[t][1] = fexp2(sS[t][1]);
        p[t][2] = fexp2(sS[t][2]);
        p[t][3] = fexp2(sS[t][3]);
      }
      union { bf16x8 v; unsigned int u[4]; } P0, P1;
      P0.u[0] = pk_trunc(p[0][0], p[0][1]);
      P0.u[1] = pk_trunc(p[0][2], p[0][3]);
      P0.u[2] = pk_trunc(p[2][0], p[2][1]);
      P0.u[3] = pk_trunc(p[2][2], p[2][3]);
      P1.u[0] = pk_trunc(p[1][0], p[1][1]);
      P1.u[1] = pk_trunc(p[1][2], p[1][3]);
      P1.u[2] = pk_trunc(p[3][0], p[3][1]);
      P1.u[3] = pk_trunc(p[3][2], p[3][3]);
      pf[gq][0] = P0.v;
      pf[gq][1] = P1.v;
      lacc[gq] = __builtin_amdgcn_mfma_f32_16x16x32_bf16(pf[gq][0], onesf.v, lacc[gq], 0, 0, 0);
      lacc[gq] = __builtin_amdgcn_mfma_f32_16x16x32_bf16(pf[gq][1], onesf.v, lacc[gq], 0, 0, 0);
    }

    // ---- O += P V, V fragments shared across the 2 q-groups ----
    __builtin_amdgcn_s_setprio(1);
#pragma unroll
    for (int t2 = 0; t2 < 4; t2++) {
      const short* vrow = Vsb + (t2 * 16 + ln) * 64;
      bf16x8 vf0 = *(const bf16x8*)(vrow + (((0 + qd) ^ (ln & 7))) * 8);
      bf16x8 vf1 = *(const bf16x8*)(vrow + (((4 + qd) ^ (ln & 7))) * 8);
#pragma unroll
      for (int gq = 0; gq < 2; gq++) {
        oA[gq][t2] = __builtin_amdgcn_mfma_f32_16x16x32_bf16(pf[gq][0], vf0, oA[gq][t2], 0, 0, 0);
        oA[gq][t2] = __builtin_amdgcn_mfma_f32_16x16x32_bf16(pf[gq][1], vf1, oA[gq][t2], 0, 0, 0);
      }
    }
    __builtin_amdgcn_s_setprio(0);

    __syncthreads();   // single barrier/tile: drains next-tile stage + read fence
  }

  // ---- epilogue: store UNNORMALIZED O + l ----
#pragma unroll
  for (int gq = 0; gq < 2; gq++) {
    int qloc = q0 + wave * 32 + gq * 16 + qd * 4;
    if (ln == 0) {
#pragma unroll
      for (int r = 0; r < 4; r++)
        lws[(size_t)(b * H_ + h) * SQS + qloc + r] = lacc[gq][r];
    }
#pragma unroll
    for (int t2 = 0; t2 < 4; t2++)
#pragma unroll
      for (int r = 0; r < 4; r++) {
        size_t idx2 = (size_t)(b * SQS + qloc + r) * DM + (h << 6) + t2 * 16 + ln;
        O0[idx2] = f2bf(oA[gq][t2][r]);
      }
  }
}

// ---------------------------------------------------------------------------
// LayerNorm(qp + O/l) * g + b -> bf16 (fused softmax-normalize + LN1)
// One wave per row; no LDS, no __syncthreads.
// ---------------------------------------------------------------------------
__global__ __launch_bounds__(256)
void ln_merge(const unsigned short* __restrict__ Xa, const unsigned short* __restrict__ O0,
              const float* __restrict__ lws,
              const float* __restrict__ gamma, const float* __restrict__ beta,
              unsigned short* __restrict__ outb)
{
  const int wv = threadIdx.x >> 6, l = threadIdx.x & 63;
  const int row = blockIdx.x * 4 + wv;
  const int b = row >> 11, q = row & 2047;
  const int hh = l >> 2;                 // head of this lane's 16-col slice
  const size_t lidx = (size_t)(b * H_ + hh) * SQS + q;
  float lsum = lws[lidx];
  float linv = (lsum > 0.f) ? 1.0f / lsum : 0.f;

  const size_t base = (size_t)row * DM + l * 16;
  float fa[16], f0[16], v[16];
  cvt8(*(const uint4*)(Xa + base),     fa);
  cvt8(*(const uint4*)(Xa + base + 8), fa + 8);
  cvt8(*(const uint4*)(O0 + base),     f0);
  cvt8(*(const uint4*)(O0 + base + 8), f0 + 8);
  float s = 0.f, s2 = 0.f;
#pragma unroll
  for (int e = 0; e < 16; e++) {
    v[e] = fa[e] + f0[e] * linv;
    s  += v[e];
    s2 += v[e] * v[e];
  }
#pragma unroll
  for (int off = 1; off < 64; off <<= 1) {
    s  += __shfl_xor(s, off);
    s2 += __shfl_xor(s2, off);
  }
  float mean = s * (1.0f / 1024.0f);
  float var  = s2 * (1.0f / 1024.0f) - mean * mean;
  float rstd = rsqrtf(var + 1e-6f);
  const int c = l * 16;
  unsigned int o[8];
#pragma unroll
  for (int e = 0; e < 8; e++) {
    float oa = (v[2 * e]     - mean) * rstd * gamma[c + 2 * e]     + beta[c + 2 * e];
    float ob = (v[2 * e + 1] - mean) * rstd * gamma[c + 2 * e + 1] + beta[c + 2 * e + 1];
    o[e] = pk_bf16(oa, ob);
  }
  uint4 o0v = {o[0], o[1], o[2], o[3]};
  uint4 o1v = {o[4], o[5], o[6], o[7]};
  *(uint4*)(outb + base)     = o0v;
  *(uint4*)(outb + base + 8) = o1v;
}

// ---------------------------------------------------------------------------
// LayerNorm(Xa + Xb) * g + b -> fp32 (final LN). One wave per row.
// ---------------------------------------------------------------------------
__global__ __launch_bounds__(256)
void ln_fuse(const unsigned short* __restrict__ Xa, const unsigned short* __restrict__ Xb,
             const float* __restrict__ gamma, const float* __restrict__ beta,
             float* __restrict__ outf)
{
  const int wv = threadIdx.x >> 6, l = threadIdx.x & 63;
  const int row = blockIdx.x * 4 + wv;
  const size_t base = (size_t)row * DM + l * 16;
  float fa[16], fb[16], v[16];
  cvt8(*(const uint4*)(Xa + base),     fa);
  cvt8(*(const uint4*)(Xa + base + 8), fa + 8);
  cvt8(*(const uint4*)(Xb + base),     fb);
  cvt8(*(const uint4*)(Xb + base + 8), fb + 8);
  float s = 0.f, s2 = 0.f;
#pragma unroll
  for (int e = 0; e < 16; e++) {
    v[e] = fa[e] + fb[e];
    s  += v[e];
    s2 += v[e] * v[e];
  }
#pragma unroll
  for (int off = 1; off < 64; off <<= 1) {
    s  += __shfl_xor(s, off);
    s2 += __shfl_xor(s2, off);
  }
  float mean = s * (1.0f / 1024.0f);
  float var  = s2 * (1.0f / 1024.0f) - mean * mean;
  float rstd = rsqrtf(var + 1e-6f);
  const int c = l * 16;
#pragma unroll
  for (int e4 = 0; e4 < 4; e4++) {
    float4 ov;
    ov.x = (v[4 * e4 + 0] - mean) * rstd * gamma[c + 4 * e4 + 0] + beta[c + 4 * e4 + 0];
    ov.y = (v[4 * e4 + 1] - mean) * rstd * gamma[c + 4 * e4 + 1] + beta[c + 4 * e4 + 1];
    ov.z = (v[4 * e4 + 2] - mean) * rstd * gamma[c + 4 * e4 + 2] + beta[c + 4 * e4 + 2];
    ov.w = (v[4 * e4 + 3] - mean) * rstd * gamma[c + 4 * e4 + 3] + beta[c + 4 * e4 + 3];
    *(float4*)(outf + base + 4 * e4) = ov;
  }
}

// ---------------------------------------------------------------------------
extern "C" void kernel_launch(void* const* d_in, const int* in_sizes, int n_in,
                              void* d_out, int out_size, void* d_ws, size_t ws_size,
                              hipStream_t stream)
{
  (void)in_sizes; (void)n_in; (void)out_size; (void)ws_size;
  const float* q    = (const float*)d_in[0];
  const float* k    = (const float*)d_in[1];
  const float* v    = (const float*)d_in[2];
  const int*   mask = (const int*)  d_in[3];
  const float* Wq   = (const float*)d_in[4];
  const float* bq   = (const float*)d_in[5];
  const float* Wk   = (const float*)d_in[6];
  const float* bk   = (const float*)d_in[7];
  const float* Wv   = (const float*)d_in[8];
  const float* bv   = (const float*)d_in[9];
  const float* Wo   = (const float*)d_in[10];
  const float* bo   = (const float*)d_in[11];
  const float* g1   = (const float*)d_in[12];
  const float* b1   = (const float*)d_in[13];
  const float* g2   = (const float*)d_in[14];
  const float* b2   = (const float*)d_in[15];

  char* ws = (char*)d_ws;
  const size_t SZ16 = (size_t)16 << 20;
  unsigned short* qi   = (unsigned short*)(ws + 0 * SZ16);
  unsigned short* ki   = (unsigned short*)(ws + 1 * SZ16);
  unsigned short* vi   = (unsigned short*)(ws + 2 * SZ16);
  unsigned short* qpb  = (unsigned short*)(ws + 3 * SZ16);
  unsigned short* kpb  = (unsigned short*)(ws + 4 * SZ16);
  unsigned short* kpc  = (unsigned short*)(ws + 5 * SZ16);   // compacted K
  unsigned short* vTb  = (unsigned short*)(ws + 6 * SZ16);
  unsigned short* Wqt  = (unsigned short*)(ws + 7 * SZ16 + ((size_t)0 << 20));
  unsigned short* Wkt  = (unsigned short*)(ws + 7 * SZ16 + ((size_t)2 << 20));
  unsigned short* Wvt  = (unsigned short*)(ws + 7 * SZ16 + ((size_t)4 << 20));
  unsigned short* Wot  = (unsigned short*)(ws + 7 * SZ16 + ((size_t)6 << 20));
  int*            idxb = (int*)           (ws + 7 * SZ16 + ((size_t)8 << 20));  // 32KB
  int*            cinfo= idxb + B_ * SKS;
  float*          lws  = (float*)         (ws + 7 * SZ16 + ((size_t)9 << 20));  // 512KB
  // dead-buffer reuse:
  unsigned short* vTc  = vi;    // free after qkv (compacted vT)
  unsigned short* O0b  = qi;    // free after qkv
  unsigned short* xb   = ki;    // free after qkv
  unsigned short* hb   = vTb;   // free after compact

  prep_all     <<<2564,             256, 0, stream>>>(q, k, v, mask, Wq, Wk, Wv, Wo,
                                                      qi, ki, vi, Wqt, Wkt, Wvt, Wot,
                                                      idxb, cinfo);

  qkv_gemm     <<<dim3(8, 64, 3),   256, 0, stream>>>(qi, ki, vi, Wqt, Wkt, Wvt,
                                                      bq, bk, bv, qpb, kpb, vTb);

  compact_kv   <<<3072,             256, 0, stream>>>(kpb, vTb, idxb, cinfo, kpc, vTc);

  attn_fwd     <<<dim3(16, 16, 4),  256, 0, stream>>>(qpb, kpc, vTc, cinfo, O0b, lws);

  ln_merge     <<<2048,             256, 0, stream>>>(qpb, O0b, lws, g1, b1, xb);
  gemm_bf16    <<<dim3(8, 64),      256, 0, stream>>>(xb, Wot, bo, hb, 1);
  ln_fuse      <<<2048,             256, 0, stream>>>(xb, hb, g2, b2, (float*)d_out);
}